// Round 4
// 1043.281 us; speedup vs baseline: 1.0131x; 1.0131x over previous
//
#include <hip/hip_runtime.h>
#include <hip/hip_bf16.h>
#include <math.h>

#ifndef M_PI
#define M_PI 3.14159265358979323846
#endif

typedef __attribute__((ext_vector_type(8))) short bf16x8;
typedef __attribute__((ext_vector_type(4))) float f32x4;

struct Filt { float f[12]; };

// ---------------------------------------------------------------------------
// Host-side kaiser-sinc filter (matches reference; FILT_UP == FILT_DOWN).
// ---------------------------------------------------------------------------
static double bessel_i0(double x) {
  double sum = 1.0, term = 1.0;
  for (int k = 1; k < 64; ++k) {
    term *= x / (2.0 * k);
    double t2 = term * term;
    sum += t2;
    if (t2 < 1e-22 * sum) break;
  }
  return sum;
}

static void compute_filter(float* out12) {
  const int ks = 12;
  const double cutoff = 0.25, half_width = 0.3;
  const int half_size = 6;
  double delta_f = 4.0 * half_width;
  double A = 2.285 * (half_size - 1) * M_PI * delta_f + 7.95;
  double beta;
  if (A > 50.0)       beta = 0.1102 * (A - 8.7);
  else if (A >= 21.0) beta = 0.5842 * pow(A - 21.0, 0.4) + 0.07886 * (A - 21.0);
  else                beta = 0.0;
  double i0b = bessel_i0(beta);
  double f[12], s = 0.0;
  for (int n = 0; n < ks; ++n) {
    double ratio = (n - (ks - 1) / 2.0) / ((ks - 1) / 2.0);
    double arg = 1.0 - ratio * ratio;
    double wnd = bessel_i0(beta * sqrt(arg > 0.0 ? arg : 0.0)) / i0b;
    double time = (n - half_size) + 0.5;
    double xx = 2.0 * cutoff * time;
    double sinc = (xx == 0.0) ? 1.0 : sin(M_PI * xx) / (M_PI * xx);
    f[n] = 2.0 * cutoff * wnd * sinc;
    s += f[n];
  }
  for (int n = 0; n < ks; ++n) out12[n] = (float)(f[n] / s);
}

__device__ __forceinline__ ushort f2bf(float f) {
  __hip_bfloat16 h = __float2bfloat16(f);
  return *(ushort*)&h;
}

__device__ __forceinline__ void gl_lds16(const void* g, void* l) {
  __builtin_amdgcn_global_load_lds(
      (const __attribute__((address_space(1))) unsigned int*)g,
      (__attribute__((address_space(3))) unsigned int*)l, 16, 0, 0);
}

// ---------------------------------------------------------------------------
// act2: fused upsample(x2,edge) -> snake_beta -> downsample(/2,edge).
// Register-resident: thread = (channel c, 8 consecutive t). Identity:
// sb[2tb-5+j], j=2m and 2m+1 both read x window xv[m..m+5]:
//   sbv[2m]   (p odd,  q=tb-3+m): 2*sum_s F[2s+1]*xv[m+s]
//   sbv[2m+1] (p even, q=tb-2+m): 2*sum_s F[2s]  *xv[m+s]
// then snake; down: acc[i] = sum_u F[u]*sbv[2i+u].
// 512 threads = 64c x 8 t-groups, 8 outputs/thread -> ~54 live floats,
// __launch_bounds__(512,4) caps VGPR<=128 -> 16 waves/CU (was 256 VGPR,
// 8 waves/CU, 10.6% occupancy -> latency-bound at 1 TB/s).
// Edge t-groups (p clamp active) take the generic wave-uniform path.
// TOUT=true : out bf16 transposed [B][T][C] (conv B-operand layout)
// TOUT=false: out fp32 [B][C][T] + residual (final stage), float4 epilogue
//             (R2/R3 bug was HERE: offset missed c0 -> channels 64+ zeroed)
// ---------------------------------------------------------------------------
template <typename TIN, bool TOUT>
__global__ __launch_bounds__(512, 4) void act2(
    const TIN* __restrict__ in, void* __restrict__ out_,
    const float* __restrict__ alpha_log, const float* __restrict__ beta_log,
    const float* __restrict__ resid, int C, int T, Filt fl)
{
  __shared__ float xs[64 * 75];  // row stride 75 (odd -> conflict-free), 74 used
  const int t0 = blockIdx.x * 64;
  const int c0 = blockIdx.y * 64;
  const int b  = blockIdx.z;
  const int tid = threadIdx.x;

  // Stage x rows: xs[c][j] = x[clamp(t0-5+j)], j<74 (coalesced along t)
  for (int i = tid; i < 64 * 74; i += 512) {
    int c = i / 74, j = i - c * 74;
    int t = min(max(t0 - 5 + j, 0), T - 1);
    xs[c * 75 + j] = (float)in[((long)(b * C + c0 + c)) * T + t];
  }
  __syncthreads();

  const int c  = tid & 63;
  const int tg = tid >> 6;        // 0..7
  const int tb = t0 + tg * 8;
  const float a  = __expf(alpha_log[c0 + c]);
  const float rb = 1.0f / (__expf(beta_log[c0 + c]) + 1e-9f);

  float sbv[26];
  // interior <=> x[tb-5 .. tb+12] unclamped and sb indices in-range (wave-uniform)
  const bool interior = (tb >= 8) && (tb <= T - 16);
  if (interior) {
    float xv[18];
    const float* xr = xs + c * 75 + tg * 8;  // xv[m] = x[tb-5+m]
#pragma unroll
    for (int m = 0; m < 18; ++m) xv[m] = xr[m];
#pragma unroll
    for (int m = 0; m <= 12; ++m) {
      float uo = fl.f[1] * xv[m]     + fl.f[3] * xv[m + 1] + fl.f[5]  * xv[m + 2]
               + fl.f[7] * xv[m + 3] + fl.f[9] * xv[m + 4] + fl.f[11] * xv[m + 5];
      float ue = fl.f[0] * xv[m]     + fl.f[2] * xv[m + 1] + fl.f[4]  * xv[m + 2]
               + fl.f[6] * xv[m + 3] + fl.f[8] * xv[m + 4] + fl.f[10] * xv[m + 5];
      uo *= 2.0f; ue *= 2.0f;
      float s0 = __sinf(a * uo);
      float s1 = __sinf(a * ue);
      sbv[2 * m]     = uo + rb * s0 * s0;
      sbv[2 * m + 1] = ue + rb * s1 * s1;
    }
  } else {
    const float* xr = xs + c * 75;  // xr[idx] = x[clamp(t0-5+idx)]
#pragma unroll
    for (int j = 0; j < 26; ++j) {
      int p = 2 * tb - 5 + j;
      int pc = min(max(p, 0), 2 * T - 1);
      float up;
      if (pc & 1) {
        int q = (pc - 1) >> 1;
        int base = q - t0 + 3;  // x[q-2]
        up = fl.f[1] * xr[base]     + fl.f[3] * xr[base + 1] + fl.f[5]  * xr[base + 2]
           + fl.f[7] * xr[base + 3] + fl.f[9] * xr[base + 4] + fl.f[11] * xr[base + 5];
      } else {
        int q = pc >> 1;
        int base = q - t0 + 2;  // x[q-3]
        up = fl.f[0] * xr[base]     + fl.f[2] * xr[base + 1] + fl.f[4]  * xr[base + 2]
           + fl.f[6] * xr[base + 3] + fl.f[8] * xr[base + 4] + fl.f[10] * xr[base + 5];
      }
      up *= 2.0f;
      float s = __sinf(a * up);
      sbv[j] = up + rb * s * s;
    }
  }

  float acc[8];
#pragma unroll
  for (int i = 0; i < 8; ++i) {
    float s = 0.0f;
#pragma unroll
    for (int u = 0; u < 12; ++u) s += fl.f[u] * sbv[2 * i + u];
    acc[i] = s;
  }

  if constexpr (TOUT) {
    __hip_bfloat16* out = (__hip_bfloat16*)out_;
#pragma unroll
    for (int i = 0; i < 8; ++i)  // lanes = 64 consecutive c -> 128B/instr
      out[((long)b * T + tb + i) * C + c0 + c] = __float2bfloat16(acc[i]);
  } else {
    float* out = (float*)out_;
    __syncthreads();            // all xs reads done before reuse
    float* ys = xs;             // ys[c][tl], stride 65 (odd)
#pragma unroll
    for (int i = 0; i < 8; ++i) ys[c * 65 + tg * 8 + i] = acc[i];
    __syncthreads();
    for (int i = tid; i < 64 * 16; i += 512) {  // 2 rounds of float4
      int cc = i >> 4, tq = (i & 15) * 4;
      long o = ((long)(b * C + c0 + cc)) * T + t0 + tq;  // c0 FIXED
      float4 r = *(const float4*)(resid + o);
      float4 v;
      v.x = ys[cc * 65 + tq]     + r.x;
      v.y = ys[cc * 65 + tq + 1] + r.y;
      v.z = ys[cc * 65 + tq + 2] + r.z;
      v.w = ys[cc * 65 + tq + 3] + r.w;
      *(float4*)(out + o) = v;
    }
  }
}

// ---------------------------------------------------------------------------
// Weight pre-conversion: w fp32 [co][ci][3] -> bf16 [d][co][ci]
// ---------------------------------------------------------------------------
__global__ __launch_bounds__(256) void wconv(
    const float* __restrict__ w, ushort* __restrict__ wbf, int C)
{
  int idx = blockIdx.x * 256 + threadIdx.x;
  int total = 3 * C * C;
  if (idx >= total) return;
  int d = idx / (C * C);
  int r = idx - d * C * C;          // co*C + ci
  wbf[idx] = f2bf(w[(long)r * 3 + d]);
}

// ---------------------------------------------------------------------------
// conv_mfma: out[b,co,t] = bias[co] + sum_{ci,d} w[co,ci,d]*in[b,ci,t-1+d]
// (zero pad). Implicit GEMM via mfma_f32_16x16x32_bf16, tap-decomposed.
// Staging pure 16B global_load_lds (full waves, wave-uniform LDS base);
// halo rows (t0-1, t0+NTC) via 8 bounds-checked ds_writes.
// ---------------------------------------------------------------------------
#define MT 64
#define NTC 256
#define BK 32

__global__ __launch_bounds__(256) void conv_mfma(
    const __hip_bfloat16* __restrict__ inT,  // [B][T][C] bf16
    const ushort* __restrict__ wbf,          // [3][C(co)][C(ci)] bf16
    const float* __restrict__ bias,
    __hip_bfloat16* __restrict__ out,        // [B][C][T] bf16
    int C, int T)
{
  __shared__ ushort wl[3][MT][BK];           // slot g=((d*64+co)*4+seg) at byte g*16
  __shared__ ushort xs[NTC + 2][BK];         // slot g=(tl*4+seg) at byte g*16
  const int t0  = blockIdx.x * NTC;
  const int co0 = blockIdx.y * MT;
  const int b   = blockIdx.z;
  const int tid  = threadIdx.x;
  const int lane = tid & 63;
  const int wave = tid >> 6;
  const int ln15 = lane & 15;
  const int quad = lane >> 4;
  const ushort* inU = (const ushort*)inT;

  f32x4 acc[4][4];
#pragma unroll
  for (int mi = 0; mi < 4; ++mi)
#pragma unroll
    for (int ni = 0; ni < 4; ++ni) acc[mi][ni] = (f32x4){0.f, 0.f, 0.f, 0.f};

  ushort* wlf = &wl[0][0][0];
  ushort* xsf = &xs[0][0];

  for (int ci0 = 0; ci0 < C; ci0 += BK) {
    __syncthreads();
    // --- weights: 768 slots of 16B, 3 full-wave iterations
#pragma unroll
    for (int it = 0; it < 3; ++it) {
      int g = it * 256 + tid;
      int d = g >> 8, co = (g >> 2) & 63, seg = g & 3;
      const ushort* gsrc = wbf + ((long)d * C + co0 + co) * C + ci0 + seg * 8;
      gl_lds16(gsrc, wlf + (size_t)(it * 256 + (tid & ~63)) * 8);
    }
    // --- input interior rows tl=1..256 (t always in-bounds): slots 4..1027
#pragma unroll
    for (int it = 0; it < 4; ++it) {
      int g = it * 256 + tid + 4;
      int tl = g >> 2, seg = g & 3;
      int t = t0 - 1 + tl;
      const ushort* gsrc = inU + ((long)b * T + t) * C + ci0 + seg * 8;
      gl_lds16(gsrc, xsf + (size_t)(it * 256 + (tid & ~63) + 4) * 8);
    }
    // --- halo rows tl=0 (t0-1) and tl=257 (t0+NTC), zero-padded
    if (tid < 8) {
      int g = (tid < 4) ? tid : (1028 + tid - 4);
      int tl = g >> 2, seg = g & 3;
      int t = t0 - 1 + tl;
      uint4 v = {0u, 0u, 0u, 0u};
      if (t >= 0 && t < T)
        v = *(const uint4*)(inU + ((long)b * T + t) * C + ci0 + seg * 8);
      *(uint4*)&xs[tl][seg * 8] = v;
    }
    __syncthreads();

#pragma unroll
    for (int d = 0; d < 3; ++d) {
      bf16x8 afr[4], bfr[4];
#pragma unroll
      for (int mi = 0; mi < 4; ++mi)
        afr[mi] = *(const bf16x8*)&wl[d][mi * 16 + ln15][quad * 8];
#pragma unroll
      for (int ni = 0; ni < 4; ++ni)
        bfr[ni] = *(const bf16x8*)&xs[wave * 64 + ni * 16 + ln15 + d][quad * 8];
#pragma unroll
      for (int mi = 0; mi < 4; ++mi)
#pragma unroll
        for (int ni = 0; ni < 4; ++ni)
          acc[mi][ni] = __builtin_amdgcn_mfma_f32_16x16x32_bf16(
              afr[mi], bfr[ni], acc[mi][ni], 0, 0, 0);
    }
  }

  // epilogue: D[m][n]: n(t)=lane&15, m(co)=quad*4+reg
#pragma unroll
  for (int mi = 0; mi < 4; ++mi) {
#pragma unroll
    for (int r = 0; r < 4; ++r) {
      int co = co0 + mi * 16 + quad * 4 + r;
      float bv = bias[co];
      long orow = ((long)(b * C + co)) * T;
#pragma unroll
      for (int ni = 0; ni < 4; ++ni) {
        int t = t0 + wave * 64 + ni * 16 + ln15;
        out[orow + t] = __float2bfloat16(acc[mi][ni][r] + bv);
      }
    }
  }
}

// ---------------------------------------------------------------------------
// Pipeline. Weight bf16 scratch lives in d_out's head (3MB), fully
// overwritten by the final act2 which writes all B*C*T floats.
// ws = 2 x 67MB bf16 ping-pong.
// ---------------------------------------------------------------------------
extern "C" void kernel_launch(void* const* d_in, const int* in_sizes, int n_in,
                              void* d_out, int out_size, void* d_ws, size_t ws_size,
                              hipStream_t stream) {
  const float* x      = (const float*)d_in[0];
  const float* w1     = (const float*)d_in[1];
  const float* b1     = (const float*)d_in[2];
  const float* w2     = (const float*)d_in[3];
  const float* b2     = (const float*)d_in[4];
  const float* alpha1 = (const float*)d_in[5];
  const float* beta1  = (const float*)d_in[6];
  const float* alpha2 = (const float*)d_in[7];
  const float* beta2  = (const float*)d_in[8];
  float* out = (float*)d_out;

  const int C = in_sizes[2];             // 512
  const long total = (long)in_sizes[0];  // B*C*T
  const int T = 8192;
  const int B = (int)(total / ((long)C * T));

  __hip_bfloat16* ws0 = (__hip_bfloat16*)d_ws;        // [B][T][C]
  __hip_bfloat16* ws1 = ws0 + (size_t)B * C * T;      // [B][C][T]
  ushort* w1bf = (ushort*)d_out;                      // scratch in out head
  ushort* w2bf = w1bf + (size_t)3 * C * C;

  Filt fl;
  compute_filter(fl.f);

  dim3 actGrid(T / 64, C / 64, B);
  dim3 convGrid(T / NTC, C / MT, B);
  int wblocks = (3 * C * C + 255) / 256;

  wconv<<<wblocks, 256, 0, stream>>>(w1, w1bf, C);
  wconv<<<wblocks, 256, 0, stream>>>(w2, w2bf, C);
  act2<float, true><<<actGrid, 512, 0, stream>>>(x, ws0, alpha1, beta1, nullptr, C, T, fl);
  conv_mfma<<<convGrid, 256, 0, stream>>>(ws0, w1bf, b1, ws1, C, T);
  act2<__hip_bfloat16, true><<<actGrid, 512, 0, stream>>>(ws1, ws0, alpha1, beta1, nullptr, C, T, fl);
  conv_mfma<<<convGrid, 256, 0, stream>>>(ws0, w2bf, b2, ws1, C, T);
  act2<__hip_bfloat16, false><<<actGrid, 512, 0, stream>>>(ws1, out, alpha2, beta2, x, C, T, fl);
}

// Round 5
// 892.152 us; speedup vs baseline: 1.1847x; 1.1694x over previous
//
#include <hip/hip_runtime.h>
#include <hip/hip_bf16.h>
#include <math.h>

#ifndef M_PI
#define M_PI 3.14159265358979323846
#endif

typedef __attribute__((ext_vector_type(8))) short bf16x8;
typedef __attribute__((ext_vector_type(4))) float f32x4;

struct Filt { float f[12]; };

// ---------------------------------------------------------------------------
// Host-side kaiser-sinc filter (matches reference; FILT_UP == FILT_DOWN).
// ---------------------------------------------------------------------------
static double bessel_i0(double x) {
  double sum = 1.0, term = 1.0;
  for (int k = 1; k < 64; ++k) {
    term *= x / (2.0 * k);
    double t2 = term * term;
    sum += t2;
    if (t2 < 1e-22 * sum) break;
  }
  return sum;
}

static void compute_filter(float* out12) {
  const int ks = 12;
  const double cutoff = 0.25, half_width = 0.3;
  const int half_size = 6;
  double delta_f = 4.0 * half_width;
  double A = 2.285 * (half_size - 1) * M_PI * delta_f + 7.95;
  double beta;
  if (A > 50.0)       beta = 0.1102 * (A - 8.7);
  else if (A >= 21.0) beta = 0.5842 * pow(A - 21.0, 0.4) + 0.07886 * (A - 21.0);
  else                beta = 0.0;
  double i0b = bessel_i0(beta);
  double f[12], s = 0.0;
  for (int n = 0; n < ks; ++n) {
    double ratio = (n - (ks - 1) / 2.0) / ((ks - 1) / 2.0);
    double arg = 1.0 - ratio * ratio;
    double wnd = bessel_i0(beta * sqrt(arg > 0.0 ? arg : 0.0)) / i0b;
    double time = (n - half_size) + 0.5;
    double xx = 2.0 * cutoff * time;
    double sinc = (xx == 0.0) ? 1.0 : sin(M_PI * xx) / (M_PI * xx);
    f[n] = 2.0 * cutoff * wnd * sinc;
    s += f[n];
  }
  for (int n = 0; n < ks; ++n) out12[n] = (float)(f[n] / s);
}

__device__ __forceinline__ ushort f2bf(float f) {
  __hip_bfloat16 h = __float2bfloat16(f);
  return *(ushort*)&h;
}

__device__ __forceinline__ void gl_lds16(const void* g, void* l) {
  __builtin_amdgcn_global_load_lds(
      (const __attribute__((address_space(1))) unsigned int*)g,
      (__attribute__((address_space(3))) unsigned int*)l, 16, 0, 0);
}

// ---------------------------------------------------------------------------
// act2: fused upsample(x2,edge) -> snake_beta -> downsample(/2,edge).
// Register-resident: thread = (channel c, 8 consecutive t). Identity:
// sb[2tb-5+j], j=2m and 2m+1 both read x window xv[m..m+5]:
//   sbv[2m]   (p odd,  q=tb-3+m): 2*sum_s F[2s+1]*xv[m+s]
//   sbv[2m+1] (p even, q=tb-2+m): 2*sum_s F[2s]  *xv[m+s]
// then snake; down: acc[i] = sum_u F[u]*sbv[2i+u].
// R4 finding: occupancy 2x (VGPR 64) gave only -6% -> NOT occupancy-bound;
// 8.6us/block vs ~3us work = latency exposure in the rolled staging loop
// (per-iter global_load -> ds_write serializes ~10 HBM latencies).
// R5 fix: batched staging (10 predicated loads issued back-to-back, then
// LDS writes -> ONE latency exposure); final stage: separate ys buffer
// (one barrier fewer) + resid float4 loads hoisted above the ys shuffle.
// TOUT=true : out bf16 transposed [B][T][C] (conv B-operand layout)
// TOUT=false: out fp32 [B][C][T] + residual (final stage), float4 epilogue
// ---------------------------------------------------------------------------
template <typename TIN, bool TOUT>
__global__ __launch_bounds__(512, 4) void act2(
    const TIN* __restrict__ in, void* __restrict__ out_,
    const float* __restrict__ alpha_log, const float* __restrict__ beta_log,
    const float* __restrict__ resid, int C, int T, Filt fl)
{
  __shared__ float xs[64 * 75];  // row stride 75 (odd -> conflict-free), 74 used
  __shared__ float ys[TOUT ? 1 : 64 * 65];  // final-stage shuffle buffer
  const int t0 = blockIdx.x * 64;
  const int c0 = blockIdx.y * 64;
  const int b  = blockIdx.z;
  const int tid = threadIdx.x;

  // Stage x rows: xs[c][j] = x[clamp(t0-5+j)], j<74 (coalesced along t).
  // Batched: issue all loads first (independent), then all LDS writes.
  constexpr int NSTG = 64 * 74;  // 4736 = 9*512 + 128
  float tmp[10];
#pragma unroll
  for (int k = 0; k < 10; ++k) {
    int i = tid + k * 512;
    if (i < NSTG) {
      int c = i / 74, j = i - c * 74;
      int t = min(max(t0 - 5 + j, 0), T - 1);
      tmp[k] = (float)in[((long)(b * C + c0 + c)) * T + t];
    }
  }
#pragma unroll
  for (int k = 0; k < 10; ++k) {
    int i = tid + k * 512;
    if (i < NSTG) {
      int c = i / 74, j = i - c * 74;
      xs[c * 75 + j] = tmp[k];
    }
  }
  __syncthreads();

  const int c  = tid & 63;
  const int tg = tid >> 6;        // 0..7
  const int tb = t0 + tg * 8;
  const float a  = __expf(alpha_log[c0 + c]);
  const float rb = 1.0f / (__expf(beta_log[c0 + c]) + 1e-9f);

  float sbv[26];
  // interior <=> x[tb-5 .. tb+12] unclamped and sb indices in-range (wave-uniform)
  const bool interior = (tb >= 8) && (tb <= T - 16);
  if (interior) {
    float xv[18];
    const float* xr = xs + c * 75 + tg * 8;  // xv[m] = x[tb-5+m]
#pragma unroll
    for (int m = 0; m < 18; ++m) xv[m] = xr[m];
#pragma unroll
    for (int m = 0; m <= 12; ++m) {
      float uo = fl.f[1] * xv[m]     + fl.f[3] * xv[m + 1] + fl.f[5]  * xv[m + 2]
               + fl.f[7] * xv[m + 3] + fl.f[9] * xv[m + 4] + fl.f[11] * xv[m + 5];
      float ue = fl.f[0] * xv[m]     + fl.f[2] * xv[m + 1] + fl.f[4]  * xv[m + 2]
               + fl.f[6] * xv[m + 3] + fl.f[8] * xv[m + 4] + fl.f[10] * xv[m + 5];
      uo *= 2.0f; ue *= 2.0f;
      float s0 = __sinf(a * uo);
      float s1 = __sinf(a * ue);
      sbv[2 * m]     = uo + rb * s0 * s0;
      sbv[2 * m + 1] = ue + rb * s1 * s1;
    }
  } else {
    const float* xr = xs + c * 75;  // xr[idx] = x[clamp(t0-5+idx)]
#pragma unroll
    for (int j = 0; j < 26; ++j) {
      int p = 2 * tb - 5 + j;
      int pc = min(max(p, 0), 2 * T - 1);
      float up;
      if (pc & 1) {
        int q = (pc - 1) >> 1;
        int base = q - t0 + 3;  // x[q-2]
        up = fl.f[1] * xr[base]     + fl.f[3] * xr[base + 1] + fl.f[5]  * xr[base + 2]
           + fl.f[7] * xr[base + 3] + fl.f[9] * xr[base + 4] + fl.f[11] * xr[base + 5];
      } else {
        int q = pc >> 1;
        int base = q - t0 + 2;  // x[q-3]
        up = fl.f[0] * xr[base]     + fl.f[2] * xr[base + 1] + fl.f[4]  * xr[base + 2]
           + fl.f[6] * xr[base + 3] + fl.f[8] * xr[base + 4] + fl.f[10] * xr[base + 5];
      }
      up *= 2.0f;
      float s = __sinf(a * up);
      sbv[j] = up + rb * s * s;
    }
  }

  float acc[8];
#pragma unroll
  for (int i = 0; i < 8; ++i) {
    float s = 0.0f;
#pragma unroll
    for (int u = 0; u < 12; ++u) s += fl.f[u] * sbv[2 * i + u];
    acc[i] = s;
  }

  if constexpr (TOUT) {
    __hip_bfloat16* out = (__hip_bfloat16*)out_;
#pragma unroll
    for (int i = 0; i < 8; ++i)  // lanes = 64 consecutive c -> 128B/instr
      out[((long)b * T + tb + i) * C + c0 + c] = __float2bfloat16(acc[i]);
  } else {
    float* out = (float*)out_;
    // Hoist resid loads: independent of ys, hide latency under the shuffle.
    const int cc0 = tid >> 4,        tq0 = (tid & 15) * 4;
    const int cc1 = cc0 + 32,        tq1 = tq0;        // i = tid + 512
    const long o0 = ((long)(b * C + c0 + cc0)) * T + t0 + tq0;
    const long o1 = ((long)(b * C + c0 + cc1)) * T + t0 + tq1;
    const float4 r0 = *(const float4*)(resid + o0);
    const float4 r1 = *(const float4*)(resid + o1);
    // ys separate from xs -> no barrier needed before writing it.
#pragma unroll
    for (int i = 0; i < 8; ++i) ys[c * 65 + tg * 8 + i] = acc[i];
    __syncthreads();
    float4 v0, v1;
    v0.x = ys[cc0 * 65 + tq0]     + r0.x;
    v0.y = ys[cc0 * 65 + tq0 + 1] + r0.y;
    v0.z = ys[cc0 * 65 + tq0 + 2] + r0.z;
    v0.w = ys[cc0 * 65 + tq0 + 3] + r0.w;
    v1.x = ys[cc1 * 65 + tq1]     + r1.x;
    v1.y = ys[cc1 * 65 + tq1 + 1] + r1.y;
    v1.z = ys[cc1 * 65 + tq1 + 2] + r1.z;
    v1.w = ys[cc1 * 65 + tq1 + 3] + r1.w;
    *(float4*)(out + o0) = v0;
    *(float4*)(out + o1) = v1;
  }
}

// ---------------------------------------------------------------------------
// Weight pre-conversion: w fp32 [co][ci][3] -> bf16 [d][co][ci]
// ---------------------------------------------------------------------------
__global__ __launch_bounds__(256) void wconv(
    const float* __restrict__ w, ushort* __restrict__ wbf, int C)
{
  int idx = blockIdx.x * 256 + threadIdx.x;
  int total = 3 * C * C;
  if (idx >= total) return;
  int d = idx / (C * C);
  int r = idx - d * C * C;          // co*C + ci
  wbf[idx] = f2bf(w[(long)r * 3 + d]);
}

// ---------------------------------------------------------------------------
// conv_mfma: out[b,co,t] = bias[co] + sum_{ci,d} w[co,ci,d]*in[b,ci,t-1+d]
// (zero pad). Implicit GEMM via mfma_f32_16x16x32_bf16, tap-decomposed.
// Staging pure 16B global_load_lds (full waves, wave-uniform LDS base);
// halo rows (t0-1, t0+NTC) via 8 bounds-checked ds_writes.
// ---------------------------------------------------------------------------
#define MT 64
#define NTC 256
#define BK 32

__global__ __launch_bounds__(256) void conv_mfma(
    const __hip_bfloat16* __restrict__ inT,  // [B][T][C] bf16
    const ushort* __restrict__ wbf,          // [3][C(co)][C(ci)] bf16
    const float* __restrict__ bias,
    __hip_bfloat16* __restrict__ out,        // [B][C][T] bf16
    int C, int T)
{
  __shared__ ushort wl[3][MT][BK];           // slot g=((d*64+co)*4+seg) at byte g*16
  __shared__ ushort xs[NTC + 2][BK];         // slot g=(tl*4+seg) at byte g*16
  const int t0  = blockIdx.x * NTC;
  const int co0 = blockIdx.y * MT;
  const int b   = blockIdx.z;
  const int tid  = threadIdx.x;
  const int lane = tid & 63;
  const int wave = tid >> 6;
  const int ln15 = lane & 15;
  const int quad = lane >> 4;
  const ushort* inU = (const ushort*)inT;

  f32x4 acc[4][4];
#pragma unroll
  for (int mi = 0; mi < 4; ++mi)
#pragma unroll
    for (int ni = 0; ni < 4; ++ni) acc[mi][ni] = (f32x4){0.f, 0.f, 0.f, 0.f};

  ushort* wlf = &wl[0][0][0];
  ushort* xsf = &xs[0][0];

  for (int ci0 = 0; ci0 < C; ci0 += BK) {
    __syncthreads();
    // --- weights: 768 slots of 16B, 3 full-wave iterations
#pragma unroll
    for (int it = 0; it < 3; ++it) {
      int g = it * 256 + tid;
      int d = g >> 8, co = (g >> 2) & 63, seg = g & 3;
      const ushort* gsrc = wbf + ((long)d * C + co0 + co) * C + ci0 + seg * 8;
      gl_lds16(gsrc, wlf + (size_t)(it * 256 + (tid & ~63)) * 8);
    }
    // --- input interior rows tl=1..256 (t always in-bounds): slots 4..1027
#pragma unroll
    for (int it = 0; it < 4; ++it) {
      int g = it * 256 + tid + 4;
      int tl = g >> 2, seg = g & 3;
      int t = t0 - 1 + tl;
      const ushort* gsrc = inU + ((long)b * T + t) * C + ci0 + seg * 8;
      gl_lds16(gsrc, xsf + (size_t)(it * 256 + (tid & ~63) + 4) * 8);
    }
    // --- halo rows tl=0 (t0-1) and tl=257 (t0+NTC), zero-padded
    if (tid < 8) {
      int g = (tid < 4) ? tid : (1028 + tid - 4);
      int tl = g >> 2, seg = g & 3;
      int t = t0 - 1 + tl;
      uint4 v = {0u, 0u, 0u, 0u};
      if (t >= 0 && t < T)
        v = *(const uint4*)(inU + ((long)b * T + t) * C + ci0 + seg * 8);
      *(uint4*)&xs[tl][seg * 8] = v;
    }
    __syncthreads();

#pragma unroll
    for (int d = 0; d < 3; ++d) {
      bf16x8 afr[4], bfr[4];
#pragma unroll
      for (int mi = 0; mi < 4; ++mi)
        afr[mi] = *(const bf16x8*)&wl[d][mi * 16 + ln15][quad * 8];
#pragma unroll
      for (int ni = 0; ni < 4; ++ni)
        bfr[ni] = *(const bf16x8*)&xs[wave * 64 + ni * 16 + ln15 + d][quad * 8];
#pragma unroll
      for (int mi = 0; mi < 4; ++mi)
#pragma unroll
        for (int ni = 0; ni < 4; ++ni)
          acc[mi][ni] = __builtin_amdgcn_mfma_f32_16x16x32_bf16(
              afr[mi], bfr[ni], acc[mi][ni], 0, 0, 0);
    }
  }

  // epilogue: D[m][n]: n(t)=lane&15, m(co)=quad*4+reg
#pragma unroll
  for (int mi = 0; mi < 4; ++mi) {
#pragma unroll
    for (int r = 0; r < 4; ++r) {
      int co = co0 + mi * 16 + quad * 4 + r;
      float bv = bias[co];
      long orow = ((long)(b * C + co)) * T;
#pragma unroll
      for (int ni = 0; ni < 4; ++ni) {
        int t = t0 + wave * 64 + ni * 16 + ln15;
        out[orow + t] = __float2bfloat16(acc[mi][ni][r] + bv);
      }
    }
  }
}

// ---------------------------------------------------------------------------
// Pipeline. Weight bf16 scratch lives in d_out's head (3MB), fully
// overwritten by the final act2 which writes all B*C*T floats.
// ws = 2 x 67MB bf16 ping-pong.
// ---------------------------------------------------------------------------
extern "C" void kernel_launch(void* const* d_in, const int* in_sizes, int n_in,
                              void* d_out, int out_size, void* d_ws, size_t ws_size,
                              hipStream_t stream) {
  const float* x      = (const float*)d_in[0];
  const float* w1     = (const float*)d_in[1];
  const float* b1     = (const float*)d_in[2];
  const float* w2     = (const float*)d_in[3];
  const float* b2     = (const float*)d_in[4];
  const float* alpha1 = (const float*)d_in[5];
  const float* beta1  = (const float*)d_in[6];
  const float* alpha2 = (const float*)d_in[7];
  const float* beta2  = (const float*)d_in[8];
  float* out = (float*)d_out;

  const int C = in_sizes[2];             // 512
  const long total = (long)in_sizes[0];  // B*C*T
  const int T = 8192;
  const int B = (int)(total / ((long)C * T));

  __hip_bfloat16* ws0 = (__hip_bfloat16*)d_ws;        // [B][T][C]
  __hip_bfloat16* ws1 = ws0 + (size_t)B * C * T;      // [B][C][T]
  ushort* w1bf = (ushort*)d_out;                      // scratch in out head
  ushort* w2bf = w1bf + (size_t)3 * C * C;

  Filt fl;
  compute_filter(fl.f);

  dim3 actGrid(T / 64, C / 64, B);
  dim3 convGrid(T / NTC, C / MT, B);
  int wblocks = (3 * C * C + 255) / 256;

  wconv<<<wblocks, 256, 0, stream>>>(w1, w1bf, C);
  wconv<<<wblocks, 256, 0, stream>>>(w2, w2bf, C);
  act2<float, true><<<actGrid, 512, 0, stream>>>(x, ws0, alpha1, beta1, nullptr, C, T, fl);
  conv_mfma<<<convGrid, 256, 0, stream>>>(ws0, w1bf, b1, ws1, C, T);
  act2<__hip_bfloat16, true><<<actGrid, 512, 0, stream>>>(ws1, ws0, alpha1, beta1, nullptr, C, T, fl);
  conv_mfma<<<convGrid, 256, 0, stream>>>(ws0, w2bf, b2, ws1, C, T);
  act2<__hip_bfloat16, false><<<actGrid, 512, 0, stream>>>(ws1, out, alpha2, beta2, x, C, T, fl);
}